// Round 3
// baseline (1326.107 us; speedup 1.0000x reference)
//
#include <hip/hip_runtime.h>
#include <cstddef>

#define B_  64
#define T_  2000
#define A_  256
#define K_  31
#define F_  32
#define TT_ 128   // t-rows per block (4 waves x 32 rows)

// tanh(x) = 1 - 2/(exp(2x)+1); saturates correctly for |x| large (rcp(inf)=0)
__device__ __forceinline__ float fast_tanh(float x) {
  float p = __expf(x + x);
  float r = __builtin_amdgcn_rcpf(p + 1.0f);
  return fmaf(-2.0f, r, 1.0f);
}

__device__ __forceinline__ float4 ld4(const float* p) {
  return *(const float4*)p;
}

// Fold conv_w*loc_w -> W2[k][a]; fold query+score_b+conv_b*loc_w -> qb[b][a]
__global__ __launch_bounds__(256) void prep_kernel(
    const float* __restrict__ conv_w, const float* __restrict__ conv_b,
    const float* __restrict__ loc_w, const float* __restrict__ query,
    const float* __restrict__ score_b, float* __restrict__ W2,
    float* __restrict__ qb) {
  const int a = threadIdx.x;
  const int blk = blockIdx.x;
  if (blk < K_) {
    float acc = 0.f;
    #pragma unroll
    for (int f = 0; f < F_; ++f) acc = fmaf(conv_w[blk * F_ + f], loc_w[f * A_ + a], acc);
    W2[blk * A_ + a] = acc;
  } else {
    const int b = blk - K_;
    float acc = 0.f;
    #pragma unroll
    for (int f = 0; f < F_; ++f) acc = fmaf(conv_b[f], loc_w[f * A_ + a], acc);
    qb[b * A_ + a] = query[b * A_ + a] + score_b[a] + acc;
  }
}

// energy[b][t] = sum_a v[a] * tanh( wmem[b][t][a] + qb[b][a] + sum_k pw[b][t+k-15]*W2[k][a] )
//
// W2 lives in LDS (31.75KB); k-outer/row-inner keeps the live register set
// ~100 VGPRs (s[36] window + pl[16] + w4[16]) so 4 waves/SIMD fit, hiding
// HBM latency and the per-row shuffle-reduce chain via TLP. (R1/R2 lesson:
// 124-VGPR W2-in-registers forced spills/low occupancy -> 73-85us.)
__global__ __launch_bounds__(256, 4) void energy_kernel(
    const float* __restrict__ wmem, const float* __restrict__ pw,
    const float* __restrict__ qb, const float* __restrict__ W2,
    const float* __restrict__ score_v, float* __restrict__ energy) {
  const int b = blockIdx.y;
  const int t0 = blockIdx.x * TT_;
  const int tid = threadIdx.x;
  const int lane = tid & 63;
  const int wv = tid >> 6;

  __shared__ __align__(16) float lds_W2[K_ * A_];   // 31*256 = 31744B
  __shared__ __align__(16) float lds_pw[TT_ + 36];

  // stage W2 into LDS (coalesced float4; 1984 vec4 / 256 threads)
  for (int idx = tid * 4; idx < K_ * A_; idx += 256 * 4)
    *(float4*)&lds_W2[idx] = ld4(W2 + idx);

  // stage the pw slice for this tile (index 0 == t0-15), zero-padded (SAME conv)
  if (tid < TT_ + 36) {
    const int g = t0 - 15 + tid;
    lds_pw[tid] = (g >= 0 && g < T_) ? pw[b * T_ + g] : 0.f;
  }
  __syncthreads();

  const float4 qb4 = ld4(qb + b * A_ + 4 * lane);
  const float4 v4  = ld4(score_v + 4 * lane);
  const float* wrow = wmem + (size_t)b * T_ * A_ + 4 * lane;
  const float* w2l  = lds_W2 + 4 * lane;

  const int rbase = 32 * wv;  // this wave's first row within the tile

  #pragma unroll 1
  for (int i = 0; i < 8; ++i) {
    const int widx = rbase + 4 * i;  // 4-aligned -> b128-aligned LDS reads

    // 4 rows of wmem (1KB/wave each, coalesced; 4 loads in flight)
    float4 w4[4];
    #pragma unroll
    for (int j = 0; j < 4; ++j) {
      const int t = t0 + widx + j;
      const int tc = t < T_ ? t : T_ - 1;  // clamp loads; store is predicated
      w4[j] = ld4(wrow + (size_t)tc * A_);
    }

    // window of pw covering rows widx..widx+3, taps 0..30 -> 35 floats
    float s[36];
    #pragma unroll
    for (int m = 0; m < 9; ++m) {
      const float4 t4 = ld4(&lds_pw[widx + 4 * m]);
      s[4 * m + 0] = t4.x; s[4 * m + 1] = t4.y;
      s[4 * m + 2] = t4.z; s[4 * m + 3] = t4.w;
    }

    // location-feature conv projected: pl[j] = sum_k s[j+k] * W2[k][a4]
    // k-outer: w2k is a 4-reg transient read from LDS, reused by 4 rows
    float4 pl[4];
    #pragma unroll
    for (int j = 0; j < 4; ++j) pl[j] = make_float4(0.f, 0.f, 0.f, 0.f);
    #pragma unroll
    for (int k = 0; k < K_; ++k) {
      const float4 w2k = ld4(w2l + k * A_);
      #pragma unroll
      for (int j = 0; j < 4; ++j) {
        pl[j].x = fmaf(s[j + k], w2k.x, pl[j].x);
        pl[j].y = fmaf(s[j + k], w2k.y, pl[j].y);
        pl[j].z = fmaf(s[j + k], w2k.z, pl[j].z);
        pl[j].w = fmaf(s[j + k], w2k.w, pl[j].w);
      }
    }

    #pragma unroll
    for (int j = 0; j < 4; ++j) {
      const int t = t0 + widx + j;
      const float tx = fast_tanh(w4[j].x + qb4.x + pl[j].x);
      const float ty = fast_tanh(w4[j].y + qb4.y + pl[j].y);
      const float tz = fast_tanh(w4[j].z + qb4.z + pl[j].z);
      const float tw = fast_tanh(w4[j].w + qb4.w + pl[j].w);
      float e = fmaf(v4.x, tx, fmaf(v4.y, ty, fmaf(v4.z, tz, v4.w * tw)));
      #pragma unroll
      for (int m = 1; m < 64; m <<= 1) e += __shfl_xor(e, m, 64);
      if (lane == 0 && t < T_) energy[b * T_ + t] = e;
    }
  }
}

// masked softmax over t + cumulative update; one block per batch row
__global__ __launch_bounds__(256) void softmax_kernel(
    const float* __restrict__ energy, const float* __restrict__ pw,
    const int* __restrict__ lens, float* __restrict__ out) {
  const int b = blockIdx.x;
  const int tid = threadIdx.x;
  const int len = lens[b];
  __shared__ float red[4];
  const float L2E = 1.4426950408889634f;

  // pass 1: max over valid t
  float mx = -3.4e38f;
  for (int t = tid; t < T_; t += 256)
    if (t < len) mx = fmaxf(mx, energy[b * T_ + t]);
  #pragma unroll
  for (int m = 1; m < 64; m <<= 1) mx = fmaxf(mx, __shfl_xor(mx, m, 64));
  if ((tid & 63) == 0) red[tid >> 6] = mx;
  __syncthreads();
  mx = fmaxf(fmaxf(red[0], red[1]), fmaxf(red[2], red[3]));
  __syncthreads();

  // pass 2: sum of exp
  float sm = 0.f;
  for (int t = tid; t < T_; t += 256)
    if (t < len) sm += __builtin_amdgcn_exp2f((energy[b * T_ + t] - mx) * L2E);
  #pragma unroll
  for (int m = 1; m < 64; m <<= 1) sm += __shfl_xor(sm, m, 64);
  if ((tid & 63) == 0) red[tid >> 6] = sm;
  __syncthreads();
  sm = red[0] + red[1] + red[2] + red[3];
  const float inv = 1.0f / sm;

  // pass 3: write output and new_weights
  for (int t = tid; t < T_; t += 256) {
    float o = 0.f;
    if (t < len)
      o = __builtin_amdgcn_exp2f((energy[b * T_ + t] - mx) * L2E) * inv;
    out[b * T_ + t] = o;
    out[B_ * T_ + b * T_ + t] = o + pw[b * T_ + t];
  }
}

extern "C" void kernel_launch(void* const* d_in, const int* in_sizes, int n_in,
                              void* d_out, int out_size, void* d_ws, size_t ws_size,
                              hipStream_t stream) {
  const float* query  = (const float*)d_in[0];
  const float* prev   = (const float*)d_in[1];
  const float* wmem   = (const float*)d_in[2];
  const int*   lens   = (const int*)d_in[3];
  const float* conv_w = (const float*)d_in[4];
  const float* conv_b = (const float*)d_in[5];
  const float* loc_w  = (const float*)d_in[6];
  const float* sv     = (const float*)d_in[7];
  const float* sb     = (const float*)d_in[8];
  float* out = (float*)d_out;
  float* ws  = (float*)d_ws;

  float* W2     = ws;                      // 31*256
  float* qb     = ws + K_ * A_;            // 64*256
  float* energy = ws + K_ * A_ + B_ * A_;  // 64*2000

  prep_kernel<<<K_ + B_, 256, 0, stream>>>(conv_w, conv_b, loc_w, query, sb, W2, qb);

  dim3 grid((T_ + TT_ - 1) / TT_, B_);  // 16 x 64
  energy_kernel<<<grid, 256, 0, stream>>>(wmem, prev, qb, W2, sv, energy);

  softmax_kernel<<<B_, 256, 0, stream>>>(energy, prev, lens, out);
}

// Round 4
// 233.010 us; speedup vs baseline: 5.6912x; 5.6912x over previous
//
#include <hip/hip_runtime.h>
#include <cstddef>

#define B_  64
#define T_  2000
#define A_  256
#define K_  31
#define F_  32
#define TT_ 128   // t-rows per block (4 waves x 32 rows)

// tanh(x) = 1 - 2/(exp(2x)+1); saturates correctly for |x| large (rcp(inf)=0)
__device__ __forceinline__ float fast_tanh(float x) {
  float p = __expf(x + x);
  float r = __builtin_amdgcn_rcpf(p + 1.0f);
  return fmaf(-2.0f, r, 1.0f);
}

__device__ __forceinline__ float4 ld4(const float* p) {
  return *(const float4*)p;
}

// force a wave-uniform float into an SGPR (value identical across lanes)
__device__ __forceinline__ float rfl(float x) {
  return __int_as_float(__builtin_amdgcn_readfirstlane(__float_as_int(x)));
}

// Fold conv_w*loc_w -> W2[k][a]; fold query+score_b+conv_b*loc_w -> qb[b][a]
__global__ __launch_bounds__(256) void prep_kernel(
    const float* __restrict__ conv_w, const float* __restrict__ conv_b,
    const float* __restrict__ loc_w, const float* __restrict__ query,
    const float* __restrict__ score_b, float* __restrict__ W2,
    float* __restrict__ qb) {
  const int a = threadIdx.x;
  const int blk = blockIdx.x;
  if (blk < K_) {
    float acc = 0.f;
    #pragma unroll
    for (int f = 0; f < F_; ++f) acc = fmaf(conv_w[blk * F_ + f], loc_w[f * A_ + a], acc);
    W2[blk * A_ + a] = acc;
  } else {
    const int b = blk - K_;
    float acc = 0.f;
    #pragma unroll
    for (int f = 0; f < F_; ++f) acc = fmaf(conv_b[f], loc_w[f * A_ + a], acc);
    qb[b * A_ + a] = query[b * A_ + a] + score_b[a] + acc;
  }
}

// energy[b][t] = sum_a v[a] * tanh( wmem[b][t][a] + qb[b][a] + sum_k pw[b][t+k-15]*W2[k][a] )
//
// W2 in LDS (31.75KB, staged once/block). pw window values are wave-uniform ->
// readfirstlane into SGPRs (v_fma takes one SGPR source), so per-lane VGPR
// live set is ~70 (pl[16]+w4[16]+transients). amdgpu_waves_per_eu(2,4) pins
// the allocator to the [128,256]-VGPR band: R3's disaster was launch_bounds'
// MIN letting the heuristic drift to 8 waves/EU = 64 VGPRs -> scratch spills
// -> 3.9GB of HBM traffic. LDS caps occupancy at 4 blocks/CU anyway.
__global__ __attribute__((amdgpu_flat_work_group_size(256, 256),
                          amdgpu_waves_per_eu(2, 4)))
void energy_kernel(
    const float* __restrict__ wmem, const float* __restrict__ pw,
    const float* __restrict__ qb, const float* __restrict__ W2,
    const float* __restrict__ score_v, float* __restrict__ energy) {
  const int b = blockIdx.y;
  const int t0 = blockIdx.x * TT_;
  const int tid = threadIdx.x;
  const int lane = tid & 63;
  const int wv = tid >> 6;

  __shared__ __align__(16) float lds_W2[K_ * A_];   // 31*256*4 = 31744B
  __shared__ __align__(16) float lds_pw[TT_ + 36];

  // stage W2 into LDS (coalesced float4; 31 iters of 1024 floats)
  for (int idx = tid * 4; idx < K_ * A_; idx += 256 * 4)
    *(float4*)&lds_W2[idx] = ld4(W2 + idx);

  // stage the pw slice for this tile (index 0 == t0-15), zero-padded (SAME conv)
  if (tid < TT_ + 36) {
    const int g = t0 - 15 + tid;
    lds_pw[tid] = (g >= 0 && g < T_) ? pw[b * T_ + g] : 0.f;
  }
  __syncthreads();

  const float4 qb4 = ld4(qb + b * A_ + 4 * lane);
  const float4 v4  = ld4(score_v + 4 * lane);
  const float* wrow = wmem + (size_t)b * T_ * A_ + 4 * lane;
  const float* w2l  = lds_W2 + 4 * lane;

  const int rbase = 32 * wv;  // this wave's first row within the tile

  #pragma unroll 1
  for (int i = 0; i < 8; ++i) {
    const int widx = rbase + 4 * i;  // 4-aligned -> b128-aligned LDS reads

    // 4 rows of wmem (1KB/wave each, coalesced; in flight during pl compute)
    float4 w4[4];
    #pragma unroll
    for (int j = 0; j < 4; ++j) {
      const int t = t0 + widx + j;
      const int tc = t < T_ ? t : T_ - 1;  // clamp loads; store is predicated
      w4[j] = ld4(wrow + (size_t)tc * A_);
    }

    // pw window for rows widx..widx+3 (taps 0..30 -> 34 floats) -> SGPRs
    float s[36];
    #pragma unroll
    for (int m = 0; m < 9; ++m) {
      const float4 t4 = ld4(&lds_pw[widx + 4 * m]);
      s[4 * m + 0] = rfl(t4.x); s[4 * m + 1] = rfl(t4.y);
      s[4 * m + 2] = rfl(t4.z); s[4 * m + 3] = rfl(t4.w);
    }

    // pl[j] = sum_k s[j+k] * W2[k][a4]; w2k is a 4-VGPR transient from LDS
    float4 pl[4];
    #pragma unroll
    for (int j = 0; j < 4; ++j) pl[j] = make_float4(0.f, 0.f, 0.f, 0.f);
    #pragma unroll
    for (int k = 0; k < K_; ++k) {
      const float4 w2k = ld4(w2l + k * A_);
      #pragma unroll
      for (int j = 0; j < 4; ++j) {
        pl[j].x = fmaf(s[j + k], w2k.x, pl[j].x);
        pl[j].y = fmaf(s[j + k], w2k.y, pl[j].y);
        pl[j].z = fmaf(s[j + k], w2k.z, pl[j].z);
        pl[j].w = fmaf(s[j + k], w2k.w, pl[j].w);
      }
    }

    #pragma unroll
    for (int j = 0; j < 4; ++j) {
      const int t = t0 + widx + j;
      const float tx = fast_tanh(w4[j].x + qb4.x + pl[j].x);
      const float ty = fast_tanh(w4[j].y + qb4.y + pl[j].y);
      const float tz = fast_tanh(w4[j].z + qb4.z + pl[j].z);
      const float tw = fast_tanh(w4[j].w + qb4.w + pl[j].w);
      float e = fmaf(v4.x, tx, fmaf(v4.y, ty, fmaf(v4.z, tz, v4.w * tw)));
      #pragma unroll
      for (int m = 1; m < 64; m <<= 1) e += __shfl_xor(e, m, 64);
      if (lane == 0 && t < T_) energy[b * T_ + t] = e;
    }
  }
}

// masked softmax over t + cumulative update; one block per batch row
__global__ __launch_bounds__(256) void softmax_kernel(
    const float* __restrict__ energy, const float* __restrict__ pw,
    const int* __restrict__ lens, float* __restrict__ out) {
  const int b = blockIdx.x;
  const int tid = threadIdx.x;
  const int len = lens[b];
  __shared__ float red[4];
  const float L2E = 1.4426950408889634f;

  // pass 1: max over valid t
  float mx = -3.4e38f;
  for (int t = tid; t < T_; t += 256)
    if (t < len) mx = fmaxf(mx, energy[b * T_ + t]);
  #pragma unroll
  for (int m = 1; m < 64; m <<= 1) mx = fmaxf(mx, __shfl_xor(mx, m, 64));
  if ((tid & 63) == 0) red[tid >> 6] = mx;
  __syncthreads();
  mx = fmaxf(fmaxf(red[0], red[1]), fmaxf(red[2], red[3]));
  __syncthreads();

  // pass 2: sum of exp
  float sm = 0.f;
  for (int t = tid; t < T_; t += 256)
    if (t < len) sm += __builtin_amdgcn_exp2f((energy[b * T_ + t] - mx) * L2E);
  #pragma unroll
  for (int m = 1; m < 64; m <<= 1) sm += __shfl_xor(sm, m, 64);
  if ((tid & 63) == 0) red[tid >> 6] = sm;
  __syncthreads();
  sm = red[0] + red[1] + red[2] + red[3];
  const float inv = 1.0f / sm;

  // pass 3: write output and new_weights
  for (int t = tid; t < T_; t += 256) {
    float o = 0.f;
    if (t < len)
      o = __builtin_amdgcn_exp2f((energy[b * T_ + t] - mx) * L2E) * inv;
    out[b * T_ + t] = o;
    out[B_ * T_ + b * T_ + t] = o + pw[b * T_ + t];
  }
}

extern "C" void kernel_launch(void* const* d_in, const int* in_sizes, int n_in,
                              void* d_out, int out_size, void* d_ws, size_t ws_size,
                              hipStream_t stream) {
  const float* query  = (const float*)d_in[0];
  const float* prev   = (const float*)d_in[1];
  const float* wmem   = (const float*)d_in[2];
  const int*   lens   = (const int*)d_in[3];
  const float* conv_w = (const float*)d_in[4];
  const float* conv_b = (const float*)d_in[5];
  const float* loc_w  = (const float*)d_in[6];
  const float* sv     = (const float*)d_in[7];
  const float* sb     = (const float*)d_in[8];
  float* out = (float*)d_out;
  float* ws  = (float*)d_ws;

  float* W2     = ws;                      // 31*256
  float* qb     = ws + K_ * A_;            // 64*256
  float* energy = ws + K_ * A_ + B_ * A_;  // 64*2000

  prep_kernel<<<K_ + B_, 256, 0, stream>>>(conv_w, conv_b, loc_w, query, sb, W2, qb);

  dim3 grid((T_ + TT_ - 1) / TT_, B_);  // 16 x 64
  energy_kernel<<<grid, 256, 0, stream>>>(wmem, prev, qb, W2, sv, energy);

  softmax_kernel<<<B_, 256, 0, stream>>>(energy, prev, lens, out);
}

// Round 5
// 222.971 us; speedup vs baseline: 5.9474x; 1.0450x over previous
//
#include <hip/hip_runtime.h>
#include <cstddef>

#define B_  64
#define T_  2000
#define A_  256
#define K_  31
#define F_  32
#define TT_ 128   // t-rows per block (4 waves x 32 rows)

// tanh(x) = 1 - 2/(exp(2x)+1); saturates correctly for |x| large (rcp(inf)=0)
__device__ __forceinline__ float fast_tanh(float x) {
  float p = __expf(x + x);
  float r = __builtin_amdgcn_rcpf(p + 1.0f);
  return fmaf(-2.0f, r, 1.0f);
}

__device__ __forceinline__ float4 ld4(const float* p) {
  return *(const float4*)p;
}

// force a wave-uniform float into an SGPR (value identical across lanes)
__device__ __forceinline__ float rfl(float x) {
  return __int_as_float(__builtin_amdgcn_readfirstlane(__float_as_int(x)));
}

// Fold conv_w*loc_w -> W2[k][a]; fold query+score_b+conv_b*loc_w -> qb[b][a]
__global__ __launch_bounds__(256) void prep_kernel(
    const float* __restrict__ conv_w, const float* __restrict__ conv_b,
    const float* __restrict__ loc_w, const float* __restrict__ query,
    const float* __restrict__ score_b, float* __restrict__ W2,
    float* __restrict__ qb) {
  const int a = threadIdx.x;
  const int blk = blockIdx.x;
  if (blk < K_) {
    float acc = 0.f;
    #pragma unroll
    for (int f = 0; f < F_; ++f) acc = fmaf(conv_w[blk * F_ + f], loc_w[f * A_ + a], acc);
    W2[blk * A_ + a] = acc;
  } else {
    const int b = blk - K_;
    float acc = 0.f;
    #pragma unroll
    for (int f = 0; f < F_; ++f) acc = fmaf(conv_b[f], loc_w[f * A_ + a], acc);
    qb[b * A_ + a] = query[b * A_ + a] + score_b[a] + acc;
  }
}

// energy[b][t] = sum_a v[a] * tanh( wmem[b][t][a] + qb[b][a] + sum_k pw[b][t+k-15]*W2[k][a] )
//
// R4 lesson: per-row 6-deep shfl chains fenced by `if(lane==0)` exec toggles
// serialized ~2400 cyc/iter of swizzle latency -> VALUBusy 53%, 74us. Here:
// (a) one interleaved multi-reduce for 4 rows (10 swizzles, 1 exec toggle),
// (b) next-iter w4 prefetch so global loads have ~1700cyc in flight.
__global__ __attribute__((amdgpu_flat_work_group_size(256, 256),
                          amdgpu_waves_per_eu(2, 4)))
void energy_kernel(
    const float* __restrict__ wmem, const float* __restrict__ pw,
    const float* __restrict__ qb, const float* __restrict__ W2,
    const float* __restrict__ score_v, float* __restrict__ energy) {
  const int b = blockIdx.y;
  const int t0 = blockIdx.x * TT_;
  const int tid = threadIdx.x;
  const int lane = tid & 63;
  const int wv = tid >> 6;

  __shared__ __align__(16) float lds_W2[K_ * A_];   // 31*256*4 = 31744B
  __shared__ __align__(16) float lds_pw[TT_ + 36];

  // stage W2 into LDS (coalesced float4)
  for (int idx = tid * 4; idx < K_ * A_; idx += 256 * 4)
    *(float4*)&lds_W2[idx] = ld4(W2 + idx);

  // stage the pw slice for this tile (index 0 == t0-15), zero-padded (SAME conv)
  if (tid < TT_ + 36) {
    const int g = t0 - 15 + tid;
    lds_pw[tid] = (g >= 0 && g < T_) ? pw[b * T_ + g] : 0.f;
  }
  __syncthreads();

  const float4 qb4 = ld4(qb + b * A_ + 4 * lane);
  const float4 v4  = ld4(score_v + 4 * lane);
  const float* wrow = wmem + (size_t)b * T_ * A_ + 4 * lane;
  const float* w2l  = lds_W2 + 4 * lane;

  const int rbase = 32 * wv;  // this wave's first row within the tile

  // prefetch iter 0's rows
  float4 w4[4], w4n[4];
  #pragma unroll
  for (int j = 0; j < 4; ++j) {
    const int t = t0 + rbase + j;
    const int tc = t < T_ ? t : T_ - 1;  // wave-uniform clamp (scalar select)
    w4[j] = ld4(wrow + (size_t)tc * A_);
  }

  #pragma unroll 2
  for (int i = 0; i < 8; ++i) {
    const int widx = rbase + 4 * i;  // 4-aligned -> b128-aligned LDS reads

    // issue next group's global loads first (in flight across this compute)
    if (i < 7) {
      #pragma unroll
      for (int j = 0; j < 4; ++j) {
        const int t = t0 + widx + 4 + j;
        const int tc = t < T_ ? t : T_ - 1;
        w4n[j] = ld4(wrow + (size_t)tc * A_);
      }
    }

    // pw window for rows widx..widx+3 (taps 0..30) -> SGPRs via readfirstlane
    float s[36];
    #pragma unroll
    for (int m = 0; m < 9; ++m) {
      const float4 t4 = ld4(&lds_pw[widx + 4 * m]);
      s[4 * m + 0] = rfl(t4.x); s[4 * m + 1] = rfl(t4.y);
      s[4 * m + 2] = rfl(t4.z); s[4 * m + 3] = rfl(t4.w);
    }

    // pl[j] = sum_k s[j+k] * W2[k][a4]; w2k is a 4-VGPR transient from LDS
    float4 pl[4];
    #pragma unroll
    for (int j = 0; j < 4; ++j) pl[j] = make_float4(0.f, 0.f, 0.f, 0.f);
    #pragma unroll
    for (int k = 0; k < K_; ++k) {
      const float4 w2k = ld4(w2l + k * A_);
      #pragma unroll
      for (int j = 0; j < 4; ++j) {
        pl[j].x = fmaf(s[j + k], w2k.x, pl[j].x);
        pl[j].y = fmaf(s[j + k], w2k.y, pl[j].y);
        pl[j].z = fmaf(s[j + k], w2k.z, pl[j].z);
        pl[j].w = fmaf(s[j + k], w2k.w, pl[j].w);
      }
    }

    // per-lane partial energies for the 4 rows (no exec-mask changes here)
    float e[4];
    #pragma unroll
    for (int j = 0; j < 4; ++j) {
      const float tx = fast_tanh(w4[j].x + qb4.x + pl[j].x);
      const float ty = fast_tanh(w4[j].y + qb4.y + pl[j].y);
      const float tz = fast_tanh(w4[j].z + qb4.z + pl[j].z);
      const float tw = fast_tanh(w4[j].w + qb4.w + pl[j].w);
      e[j] = fmaf(v4.x, tx, fmaf(v4.y, ty, fmaf(v4.z, tz, v4.w * tw)));
    }

    // rotate prefetch buffer (renamed away under unroll)
    #pragma unroll
    for (int j = 0; j < 4; ++j) w4[j] = w4n[j];

    // interleaved 4-row multi-reduce: xor32+sel, xor16+sel, then xor8/4/2/1.
    // After this, the 16-lane group g = lane>>4 holds sum for row widx+g.
    float m0 = e[0] + __shfl_xor(e[0], 32);
    float m1 = e[1] + __shfl_xor(e[1], 32);
    float m2 = e[2] + __shfl_xor(e[2], 32);
    float m3 = e[3] + __shfl_xor(e[3], 32);
    const bool hi32 = (lane & 32) != 0;
    float n0 = hi32 ? m2 : m0;
    float n1 = hi32 ? m3 : m1;
    float q0 = n0 + __shfl_xor(n0, 16);
    float q1 = n1 + __shfl_xor(n1, 16);
    float p = (lane & 16) ? q1 : q0;
    p += __shfl_xor(p, 8);
    p += __shfl_xor(p, 4);
    p += __shfl_xor(p, 2);
    p += __shfl_xor(p, 1);

    const int tr = t0 + widx + (lane >> 4);
    if ((lane & 15) == 0 && tr < T_) energy[b * T_ + tr] = p;
  }
}

// masked softmax over t + cumulative update; one block per batch row
__global__ __launch_bounds__(256) void softmax_kernel(
    const float* __restrict__ energy, const float* __restrict__ pw,
    const int* __restrict__ lens, float* __restrict__ out) {
  const int b = blockIdx.x;
  const int tid = threadIdx.x;
  const int len = lens[b];
  __shared__ float red[4];
  const float L2E = 1.4426950408889634f;

  // pass 1: max over valid t
  float mx = -3.4e38f;
  for (int t = tid; t < T_; t += 256)
    if (t < len) mx = fmaxf(mx, energy[b * T_ + t]);
  #pragma unroll
  for (int m = 1; m < 64; m <<= 1) mx = fmaxf(mx, __shfl_xor(mx, m, 64));
  if ((tid & 63) == 0) red[tid >> 6] = mx;
  __syncthreads();
  mx = fmaxf(fmaxf(red[0], red[1]), fmaxf(red[2], red[3]));
  __syncthreads();

  // pass 2: sum of exp
  float sm = 0.f;
  for (int t = tid; t < T_; t += 256)
    if (t < len) sm += __builtin_amdgcn_exp2f((energy[b * T_ + t] - mx) * L2E);
  #pragma unroll
  for (int m = 1; m < 64; m <<= 1) sm += __shfl_xor(sm, m, 64);
  if ((tid & 63) == 0) red[tid >> 6] = sm;
  __syncthreads();
  sm = red[0] + red[1] + red[2] + red[3];
  const float inv = 1.0f / sm;

  // pass 3: write output and new_weights
  for (int t = tid; t < T_; t += 256) {
    float o = 0.f;
    if (t < len)
      o = __builtin_amdgcn_exp2f((energy[b * T_ + t] - mx) * L2E) * inv;
    out[b * T_ + t] = o;
    out[B_ * T_ + b * T_ + t] = o + pw[b * T_ + t];
  }
}

extern "C" void kernel_launch(void* const* d_in, const int* in_sizes, int n_in,
                              void* d_out, int out_size, void* d_ws, size_t ws_size,
                              hipStream_t stream) {
  const float* query  = (const float*)d_in[0];
  const float* prev   = (const float*)d_in[1];
  const float* wmem   = (const float*)d_in[2];
  const int*   lens   = (const int*)d_in[3];
  const float* conv_w = (const float*)d_in[4];
  const float* conv_b = (const float*)d_in[5];
  const float* loc_w  = (const float*)d_in[6];
  const float* sv     = (const float*)d_in[7];
  const float* sb     = (const float*)d_in[8];
  float* out = (float*)d_out;
  float* ws  = (float*)d_ws;

  float* W2     = ws;                      // 31*256
  float* qb     = ws + K_ * A_;            // 64*256
  float* energy = ws + K_ * A_ + B_ * A_;  // 64*2000

  prep_kernel<<<K_ + B_, 256, 0, stream>>>(conv_w, conv_b, loc_w, query, sb, W2, qb);

  dim3 grid((T_ + TT_ - 1) / TT_, B_);  // 16 x 64
  energy_kernel<<<grid, 256, 0, stream>>>(wmem, prev, qb, W2, sv, energy);

  softmax_kernel<<<B_, 256, 0, stream>>>(energy, prev, lens, out);
}